// Round 1
// baseline (118.506 us; speedup 1.0000x reference)
//
#include <hip/hip_runtime.h>
#include <math.h>

#define B_   8
#define L_   512
#define DIN  1024
#define H_   128
#define HEAD 64
#define NL   16
#define INF_ 1.0e12f

// ws layout (float offsets)
#define SIN_OFF  0
#define COS_OFF  (512*32)
#define QROT_OFF (COS_OFF + 512*32)            // 32768
#define KROT_OFF (QROT_OFF + B_*L_*HEAD)       // + 262144
#define BQ_OFF   (KROT_OFF + B_*L_*HEAD)       // odd channels -> added along m
#define BK_OFF   (BQ_OFF + B_*NL*L_)           // even channels -> added along n
#define QK_OFF   (BK_OFF + B_*NL*L_)
// total floats = QK_OFF + B_*L_*L_ = 2,785,280  (~10.6 MB)

// --------------------------------------------------------------------------
// K1: rotary sin/cos table in f64 (pos 0..511, freq idx 0..31)
__global__ void rope_table_kernel(float* __restrict__ ws) {
    int idx = blockIdx.x * 256 + threadIdx.x;
    if (idx >= 512 * 32) return;
    int m = idx >> 5, i = idx & 31;
    double ang = (double)m * pow(10000.0, -(double)i / 32.0);
    ws[SIN_OFF + idx] = (float)sin(ang);
    ws[COS_OFF + idx] = (float)cos(ang);
}

// --------------------------------------------------------------------------
// K2: h = X@W1 + b1 (BM=16, BN=128 full, BK=32), then rotary + bias epilogue.
__global__ __launch_bounds__(256) void gemm1_fused_kernel(
    const float* __restrict__ X, const float* __restrict__ W1,
    const float* __restrict__ b1, const float* __restrict__ W2,
    const float* __restrict__ b2, float* __restrict__ ws)
{
    __shared__ float As[32][17];     // [k][m]
    __shared__ float Bs[32][128];    // [k][n]
    __shared__ float hs[16][129];    // h tile
    __shared__ float W2s[128 * 32];

    const int tid = threadIdx.x;
    const int m0  = blockIdx.x * 16;

    // stage W2 (128x32) into LDS
    {
        const float4* w2v = (const float4*)W2;
        float4* w2sv = (float4*)W2s;
        for (int f = tid; f < 1024; f += 256) w2sv[f] = w2v[f];
    }

    const int ty = tid >> 5;   // 0..7  -> rows ty*2, ty*2+1
    const int tx = tid & 31;   // 0..31 -> cols tx*4..tx*4+3
    float acc[2][4] = {};

    for (int k0 = 0; k0 < DIN; k0 += 32) {
        // A tile: 16 rows x 32 k
        {
            int ar = tid >> 5;           // 0..7
            int ak = tid & 31;
            As[ak][ar]     = X[(size_t)(m0 + ar)     * DIN + k0 + ak];
            As[ak][ar + 8] = X[(size_t)(m0 + ar + 8) * DIN + k0 + ak];
        }
        // B tile: 32 k x 128 n
        {
            int br = tid >> 5;           // rows br, br+8, br+16, br+24
            int bc = (tid & 31) * 4;
            #pragma unroll
            for (int rr = 0; rr < 4; rr++) {
                float4 v = *(const float4*)&W1[(size_t)(k0 + br + rr * 8) * H_ + bc];
                *(float4*)&Bs[br + rr * 8][bc] = v;
            }
        }
        __syncthreads();
        #pragma unroll
        for (int kk = 0; kk < 32; kk++) {
            float a0 = As[kk][ty * 2];
            float a1 = As[kk][ty * 2 + 1];
            float4 bv = *(const float4*)&Bs[kk][tx * 4];
            acc[0][0] += a0 * bv.x; acc[0][1] += a0 * bv.y;
            acc[0][2] += a0 * bv.z; acc[0][3] += a0 * bv.w;
            acc[1][0] += a1 * bv.x; acc[1][1] += a1 * bv.y;
            acc[1][2] += a1 * bv.z; acc[1][3] += a1 * bv.w;
        }
        __syncthreads();
    }

    // + b1, park h tile in LDS
    #pragma unroll
    for (int r = 0; r < 2; r++) {
        #pragma unroll
        for (int c = 0; c < 4; c++)
            hs[ty * 2 + r][tx * 4 + c] = acc[r][c] + b1[tx * 4 + c];
    }
    __syncthreads();

    // rotary: thread -> (row 0..15, j 0..15); outputs d = 4j..4j+3
    {
        int row = tid >> 4;
        int j   = tid & 15;
        int g   = m0 + row;
        int pos = g & (L_ - 1);
        float h0 = hs[row][8 * j + 0], h1 = hs[row][8 * j + 1];
        float h2 = hs[row][8 * j + 2], h3 = hs[row][8 * j + 3];
        float h4 = hs[row][8 * j + 4], h5 = hs[row][8 * j + 5];
        float h6 = hs[row][8 * j + 6], h7 = hs[row][8 * j + 7];
        float s0 = ws[SIN_OFF + pos * 32 + 2 * j];
        float c0 = ws[COS_OFF + pos * 32 + 2 * j];
        float s1 = ws[SIN_OFF + pos * 32 + 2 * j + 1];
        float c1 = ws[COS_OFF + pos * 32 + 2 * j + 1];
        float4 q, k;
        q.x = h0 * c0 - h2 * s0;  q.y = h2 * c0 + h0 * s0;
        q.z = h4 * c1 - h6 * s1;  q.w = h6 * c1 + h4 * s1;
        k.x = h1 * c0 - h3 * s0;  k.y = h3 * c0 + h1 * s0;
        k.z = h5 * c1 - h7 * s1;  k.w = h7 * c1 + h5 * s1;
        *(float4*)&ws[QROT_OFF + (size_t)g * HEAD + 4 * j] = q;
        *(float4*)&ws[KROT_OFF + (size_t)g * HEAD + 4 * j] = k;
    }

    // bias: 16 rows x 32 outs; o even -> biasK (per n), o odd -> biasQ (per m)
    for (int idx = tid; idx < 16 * 32; idx += 256) {
        int row = idx >> 5;
        int o   = idx & 31;
        float sum = b2[o];
        #pragma unroll 8
        for (int c = 0; c < H_; c++) sum += hs[row][c] * W2s[c * 32 + o];
        sum *= 0.5f;
        int g = m0 + row;
        int bb = g >> 9;
        int pos = g & (L_ - 1);
        if (o & 1) ws[BQ_OFF + ((size_t)bb * NL + (o >> 1)) * L_ + pos] = sum;
        else       ws[BK_OFF + ((size_t)bb * NL + (o >> 1)) * L_ + pos] = sum;
    }
}

// --------------------------------------------------------------------------
// K3: qk[b,m,n] = dot(qrot[b,m,:], krot[b,n,:]) * 0.125; 64x64 tiles, K=64.
__global__ __launch_bounds__(256) void qk_kernel(float* __restrict__ ws)
{
    __shared__ float Qs[64][68];   // [d][m], padded so float4 rows stay aligned
    __shared__ float Ks[64][68];   // [d][n]

    const int tid = threadIdx.x;
    const int bid = blockIdx.x;
    const int bb = bid >> 6;
    const int mt = (bid >> 3) & 7;
    const int nt = bid & 7;
    const int m0 = mt * 64, n0 = nt * 64;

    // stage transposed
    {
        int r0   = tid >> 4;          // 0..15 (rows r0, r0+16, r0+32, r0+48)
        int dcol = (tid & 15) * 4;
        #pragma unroll
        for (int rr = 0; rr < 4; rr++) {
            int r = r0 + rr * 16;
            float4 q = *(const float4*)&ws[QROT_OFF + ((size_t)(bb * L_ + m0 + r)) * HEAD + dcol];
            float4 k = *(const float4*)&ws[KROT_OFF + ((size_t)(bb * L_ + n0 + r)) * HEAD + dcol];
            Qs[dcol + 0][r] = q.x; Qs[dcol + 1][r] = q.y;
            Qs[dcol + 2][r] = q.z; Qs[dcol + 3][r] = q.w;
            Ks[dcol + 0][r] = k.x; Ks[dcol + 1][r] = k.y;
            Ks[dcol + 2][r] = k.z; Ks[dcol + 3][r] = k.w;
        }
    }
    __syncthreads();

    const int ty = tid >> 4;   // m micro: ty*4..+3
    const int tx = tid & 15;   // n micro: tx*4..+3
    float acc[4][4] = {};
    #pragma unroll 8
    for (int d = 0; d < HEAD; d++) {
        float4 a  = *(const float4*)&Qs[d][ty * 4];
        float4 bv = *(const float4*)&Ks[d][tx * 4];
        acc[0][0] += a.x * bv.x; acc[0][1] += a.x * bv.y; acc[0][2] += a.x * bv.z; acc[0][3] += a.x * bv.w;
        acc[1][0] += a.y * bv.x; acc[1][1] += a.y * bv.y; acc[1][2] += a.y * bv.z; acc[1][3] += a.y * bv.w;
        acc[2][0] += a.z * bv.x; acc[2][1] += a.z * bv.y; acc[2][2] += a.z * bv.z; acc[2][3] += a.z * bv.w;
        acc[3][0] += a.w * bv.x; acc[3][1] += a.w * bv.y; acc[3][2] += a.w * bv.z; acc[3][3] += a.w * bv.w;
    }

    #pragma unroll
    for (int r = 0; r < 4; r++) {
        float4 o;
        o.x = acc[r][0] * 0.125f; o.y = acc[r][1] * 0.125f;
        o.z = acc[r][2] * 0.125f; o.w = acc[r][3] * 0.125f;
        *(float4*)&ws[QK_OFF + ((size_t)(bb * L_ + m0 + ty * 4 + r)) * L_ + n0 + tx * 4] = o;
    }
}

// --------------------------------------------------------------------------
// K4: out[b,l,m,n] = qk[b,m,n] + biasK[b,l,n] + biasQ[b,l,m] - masks
__global__ __launch_bounds__(128) void bcast_kernel(
    const int* __restrict__ am, const float* __restrict__ ws, float* __restrict__ out)
{
    const int bm = blockIdx.x;
    const int bb = bm >> 9;
    const int m  = bm & (L_ - 1);
    const int n0 = threadIdx.x * 4;

    float4 qk4 = *(const float4*)&ws[QK_OFF + ((size_t)(bb * L_ + m)) * L_ + n0];
    float amm = (float)am[bb * L_ + m];
    int4 amn = *(const int4*)&am[bb * L_ + n0];

    float4 base;
    base.x = qk4.x - (1.0f - amm * (float)amn.x) * INF_ - ((n0 + 0 < m) ? INF_ : 0.0f);
    base.y = qk4.y - (1.0f - amm * (float)amn.y) * INF_ - ((n0 + 1 < m) ? INF_ : 0.0f);
    base.z = qk4.z - (1.0f - amm * (float)amn.z) * INF_ - ((n0 + 2 < m) ? INF_ : 0.0f);
    base.w = qk4.w - (1.0f - amm * (float)amn.w) * INF_ - ((n0 + 3 < m) ? INF_ : 0.0f);

    #pragma unroll
    for (int l = 0; l < NL; l++) {
        float  bq  = ws[BQ_OFF + ((size_t)bb * NL + l) * L_ + m];
        float4 bk4 = *(const float4*)&ws[BK_OFF + ((size_t)bb * NL + l) * L_ + n0];
        float4 o;
        o.x = base.x + bk4.x + bq;
        o.y = base.y + bk4.y + bq;
        o.z = base.z + bk4.z + bq;
        o.w = base.w + bk4.w + bq;
        *(float4*)&out[(((size_t)(bb * NL + l)) * L_ + m) * L_ + n0] = o;
    }
}

// --------------------------------------------------------------------------
extern "C" void kernel_launch(void* const* d_in, const int* in_sizes, int n_in,
                              void* d_out, int out_size, void* d_ws, size_t ws_size,
                              hipStream_t stream) {
    const float* X  = (const float*)d_in[0];
    const int*   am = (const int*)d_in[1];
    const float* W1 = (const float*)d_in[2];
    const float* b1 = (const float*)d_in[3];
    const float* W2 = (const float*)d_in[4];
    const float* b2 = (const float*)d_in[5];
    float* out = (float*)d_out;
    float* ws  = (float*)d_ws;

    rope_table_kernel<<<64, 256, 0, stream>>>(ws);
    gemm1_fused_kernel<<<(B_ * L_) / 16, 256, 0, stream>>>(X, W1, b1, W2, b2, ws);
    qk_kernel<<<B_ * (L_ / 64) * (L_ / 64), 256, 0, stream>>>(ws);
    bcast_kernel<<<B_ * L_, 128, 0, stream>>>(am, ws, out);
}

// Round 2
// 60.704 us; speedup vs baseline: 1.9522x; 1.9522x over previous
//
#include <hip/hip_runtime.h>
#include <math.h>

#define B_   8
#define L_   512
#define DIN  1024
#define H_   128
#define HEAD 64
#define NL   16
#define INF_ 1.0e12f

// ws layout (float offsets)
#define SIN_OFF  0
#define COS_OFF  (512*32)
#define QROT_OFF (COS_OFF + 512*32)            // 32768
#define KROT_OFF (QROT_OFF + B_*L_*HEAD)       // + 262144
#define BQ_OFF   (KROT_OFF + B_*L_*HEAD)       // odd channels -> added along m
#define BK_OFF   (BQ_OFF + B_*NL*L_)           // even channels -> added along n
#define QK_OFF   (BK_OFF + B_*NL*L_)
#define W1T_OFF  (QK_OFF + B_*L_*L_)           // bf16 [128][1024] = 32768 floats
// total floats = W1T_OFF + 32768 = 2,818,048 (~11.3 MB)

typedef float          floatx4  __attribute__((ext_vector_type(4)));
typedef short          shortx8  __attribute__((ext_vector_type(8)));
typedef unsigned short ushortx8 __attribute__((ext_vector_type(8)));

__device__ __forceinline__ unsigned short f2bf(float f) {
    unsigned u = __float_as_uint(f);
    u += 0x7FFFu + ((u >> 16) & 1u);   // RNE
    return (unsigned short)(u >> 16);
}

// --------------------------------------------------------------------------
// K1: rotary sin/cos table in f64 (pos 0..511, freq idx 0..31)
__global__ void rope_table_kernel(float* __restrict__ ws) {
    int idx = blockIdx.x * 256 + threadIdx.x;
    if (idx >= 512 * 32) return;
    int m = idx >> 5, i = idx & 31;
    double ang = (double)m * pow(10000.0, -(double)i / 32.0);
    ws[SIN_OFF + idx] = (float)sin(ang);
    ws[COS_OFF + idx] = (float)cos(ang);
}

// --------------------------------------------------------------------------
// K1b: W1 (1024x128 f32) -> W1T bf16 [n=128][k=1024]; 16 blocks, 64 k-rows each
__global__ __launch_bounds__(256) void w1t_kernel(const float* __restrict__ W1,
                                                  float* __restrict__ ws) {
    __shared__ float lds[64 * 132];
    const int tid = threadIdx.x;
    const int k0  = blockIdx.x * 64;
    // load 64 rows x 128 cols coalesced
    for (int i = 0; i < 8; i++) {
        int f = tid + i * 256;              // float4 index over 2048
        int k = f >> 5, n4 = (f & 31) * 4;
        *(float4*)&lds[k * 132 + n4] = *(const float4*)&W1[(size_t)(k0 + k) * H_ + n4];
    }
    __syncthreads();
    unsigned short* W1T = (unsigned short*)(ws + W1T_OFF);
    const int n = tid >> 1;
    const int kh = (tid & 1) * 32;
    for (int i = 0; i < 4; i++) {
        ushortx8 p;
        #pragma unroll
        for (int j = 0; j < 8; j++) p[j] = f2bf(lds[(kh + i * 8 + j) * 132 + n]);
        *(ushortx8*)&W1T[(size_t)n * DIN + k0 + kh + i * 8] = p;
    }
}

// --------------------------------------------------------------------------
// K2: h = X@W1 + b1 via bf16 MFMA, then rotary + bias epilogue. BM=16, BK=128.
__global__ __launch_bounds__(256) void gemm1_fused_kernel(
    const float* __restrict__ X, const float* __restrict__ b1,
    const float* __restrict__ W2, const float* __restrict__ b2,
    float* __restrict__ ws)
{
    __shared__ unsigned short As[16 * 128];    // swizzled bf16 A tile
    __shared__ unsigned short Bs[128 * 128];   // swizzled bf16 B tile (W1T rows)
    __shared__ float hs[16 * 132];
    __shared__ float W2sT[32 * 132];

    const int tid = threadIdx.x;
    const int m0  = blockIdx.x * 16;
    const unsigned short* W1T = (const unsigned short*)(ws + W1T_OFF);

    // stage W2 transposed+padded
    for (int f = tid; f < 4096; f += 256) {
        int c = f >> 5, o = f & 31;
        W2sT[o * 132 + c] = W2[f];
    }

    // staging thread mappings
    const int am  = tid >> 4;            // A row 0..15
    const int akc = (tid & 15) * 8;      // A k-chunk (floats/ushorts)
    const int bn  = tid >> 1;            // B row (n) 0..127
    const int bk0 = (tid & 1) * 64;      // B k-half

    const int w    = tid >> 6;
    const int lane = tid & 63;
    const int lrow = lane >> 4;          // 0..3
    const int lcol = lane & 15;          // 0..15

    float4   xa[2], xb[2];
    ushortx8 wb[2][8];

    // prefetch iter 0
    {
        const float4* xp = (const float4*)(X + (size_t)(m0 + am) * DIN + akc);
        xa[0] = xp[0]; xb[0] = xp[1];
        const ushortx8* wp = (const ushortx8*)(W1T + (size_t)bn * DIN + bk0);
        #pragma unroll
        for (int i = 0; i < 8; i++) wb[0][i] = wp[i];
    }

    floatx4 acc0 = {0.f, 0.f, 0.f, 0.f};
    floatx4 acc1 = {0.f, 0.f, 0.f, 0.f};

    #pragma unroll
    for (int it = 0; it < 8; it++) {
        const int cur = it & 1, nxt = cur ^ 1;
        // prefetch next K-tile into alternate regs
        if (it < 7) {
            const float4* xp = (const float4*)(X + (size_t)(m0 + am) * DIN + (it + 1) * 128 + akc);
            xa[nxt] = xp[0]; xb[nxt] = xp[1];
            const ushortx8* wp = (const ushortx8*)(W1T + (size_t)bn * DIN + (it + 1) * 128 + bk0);
            #pragma unroll
            for (int i = 0; i < 8; i++) wb[nxt][i] = wp[i];
        }
        __syncthreads();   // LDS free (previous reads done)
        // write A (cvt f32->bf16), swizzled
        {
            ushortx8 pa;
            pa[0] = f2bf(xa[cur].x); pa[1] = f2bf(xa[cur].y);
            pa[2] = f2bf(xa[cur].z); pa[3] = f2bf(xa[cur].w);
            pa[4] = f2bf(xb[cur].x); pa[5] = f2bf(xb[cur].y);
            pa[6] = f2bf(xb[cur].z); pa[7] = f2bf(xb[cur].w);
            *(ushortx8*)&As[am * 128 + (akc ^ ((am & 7) << 3))] = pa;
        }
        // write B, swizzled
        #pragma unroll
        for (int i = 0; i < 8; i++) {
            int k = bk0 + i * 8;
            *(ushortx8*)&Bs[bn * 128 + (k ^ ((bn & 7) << 3))] = wb[cur][i];
        }
        __syncthreads();   // LDS ready
        // 4 K-steps of 32
        #pragma unroll
        for (int s = 0; s < 4; s++) {
            const int ka = s * 32 + lrow * 8;
            shortx8 af = *(const shortx8*)&As[lcol * 128 + (ka ^ ((lcol & 7) << 3))];
            const int n0f = w * 32 + lcol;
            shortx8 bf0 = *(const shortx8*)&Bs[n0f * 128 + (ka ^ ((n0f & 7) << 3))];
            const int n1f = n0f + 16;
            shortx8 bf1 = *(const shortx8*)&Bs[n1f * 128 + (ka ^ ((n1f & 7) << 3))];
            acc0 = __builtin_amdgcn_mfma_f32_16x16x32_bf16(af, bf0, acc0, 0, 0, 0);
            acc1 = __builtin_amdgcn_mfma_f32_16x16x32_bf16(af, bf1, acc1, 0, 0, 0);
        }
    }

    // acc -> hs (+b1). C layout: col=lane&15, row=(lane>>4)*4+r  [m89]
    {
        float b1a = b1[w * 32 + lcol];
        float b1b = b1[w * 32 + 16 + lcol];
        #pragma unroll
        for (int r = 0; r < 4; r++) {
            hs[(lrow * 4 + r) * 132 + w * 32 + lcol]      = acc0[r] + b1a;
            hs[(lrow * 4 + r) * 132 + w * 32 + 16 + lcol] = acc1[r] + b1b;
        }
    }
    __syncthreads();

    // rotary: thread -> (row 0..15, j 0..15); outputs d = 4j..4j+3
    {
        int row = tid >> 4;
        int j   = tid & 15;
        int g   = m0 + row;
        int pos = g & (L_ - 1);
        const float* hr = &hs[row * 132];
        float h0 = hr[8 * j + 0], h1 = hr[8 * j + 1];
        float h2 = hr[8 * j + 2], h3 = hr[8 * j + 3];
        float h4 = hr[8 * j + 4], h5 = hr[8 * j + 5];
        float h6 = hr[8 * j + 6], h7 = hr[8 * j + 7];
        float s0 = ws[SIN_OFF + pos * 32 + 2 * j];
        float c0 = ws[COS_OFF + pos * 32 + 2 * j];
        float s1 = ws[SIN_OFF + pos * 32 + 2 * j + 1];
        float c1 = ws[COS_OFF + pos * 32 + 2 * j + 1];
        float4 q, k;
        q.x = h0 * c0 - h2 * s0;  q.y = h2 * c0 + h0 * s0;
        q.z = h4 * c1 - h6 * s1;  q.w = h6 * c1 + h4 * s1;
        k.x = h1 * c0 - h3 * s0;  k.y = h3 * c0 + h1 * s0;
        k.z = h5 * c1 - h7 * s1;  k.w = h7 * c1 + h5 * s1;
        *(float4*)&ws[QROT_OFF + (size_t)g * HEAD + 4 * j] = q;
        *(float4*)&ws[KROT_OFF + (size_t)g * HEAD + 4 * j] = k;
    }

    // bias: 16 rows x 32 outs; o even -> biasK (per n), o odd -> biasQ (per m)
    for (int idx = tid; idx < 16 * 32; idx += 256) {
        int row = idx >> 5;
        int o   = idx & 31;
        float sum = b2[o];
        #pragma unroll
        for (int c = 0; c < H_; c += 4) {
            float4 h4 = *(const float4*)&hs[row * 132 + c];
            float4 w4 = *(const float4*)&W2sT[o * 132 + c];
            sum += h4.x * w4.x + h4.y * w4.y + h4.z * w4.z + h4.w * w4.w;
        }
        sum *= 0.5f;
        int g = m0 + row;
        int bb = g >> 9;
        int pos = g & (L_ - 1);
        if (o & 1) ws[BQ_OFF + ((size_t)bb * NL + (o >> 1)) * L_ + pos] = sum;
        else       ws[BK_OFF + ((size_t)bb * NL + (o >> 1)) * L_ + pos] = sum;
    }
}

// --------------------------------------------------------------------------
// K3: qk[b,m,n] = dot(qrot[b,m,:], krot[b,n,:]) * 0.125; 64x64 tiles, K=64.
__global__ __launch_bounds__(256) void qk_kernel(float* __restrict__ ws)
{
    __shared__ float Qs[64][68];
    __shared__ float Ks[64][68];

    const int tid = threadIdx.x;
    const int bid = blockIdx.x;
    const int bb = bid >> 6;
    const int mt = (bid >> 3) & 7;
    const int nt = bid & 7;
    const int m0 = mt * 64, n0 = nt * 64;

    {
        int r0   = tid >> 4;
        int dcol = (tid & 15) * 4;
        #pragma unroll
        for (int rr = 0; rr < 4; rr++) {
            int r = r0 + rr * 16;
            float4 q = *(const float4*)&ws[QROT_OFF + ((size_t)(bb * L_ + m0 + r)) * HEAD + dcol];
            float4 k = *(const float4*)&ws[KROT_OFF + ((size_t)(bb * L_ + n0 + r)) * HEAD + dcol];
            Qs[dcol + 0][r] = q.x; Qs[dcol + 1][r] = q.y;
            Qs[dcol + 2][r] = q.z; Qs[dcol + 3][r] = q.w;
            Ks[dcol + 0][r] = k.x; Ks[dcol + 1][r] = k.y;
            Ks[dcol + 2][r] = k.z; Ks[dcol + 3][r] = k.w;
        }
    }
    __syncthreads();

    const int ty = tid >> 4;
    const int tx = tid & 15;
    float acc[4][4] = {};
    #pragma unroll 8
    for (int d = 0; d < HEAD; d++) {
        float4 a  = *(const float4*)&Qs[d][ty * 4];
        float4 bv = *(const float4*)&Ks[d][tx * 4];
        acc[0][0] += a.x * bv.x; acc[0][1] += a.x * bv.y; acc[0][2] += a.x * bv.z; acc[0][3] += a.x * bv.w;
        acc[1][0] += a.y * bv.x; acc[1][1] += a.y * bv.y; acc[1][2] += a.y * bv.z; acc[1][3] += a.y * bv.w;
        acc[2][0] += a.z * bv.x; acc[2][1] += a.z * bv.y; acc[2][2] += a.z * bv.z; acc[2][3] += a.z * bv.w;
        acc[3][0] += a.w * bv.x; acc[3][1] += a.w * bv.y; acc[3][2] += a.w * bv.z; acc[3][3] += a.w * bv.w;
    }

    #pragma unroll
    for (int r = 0; r < 4; r++) {
        float4 o;
        o.x = acc[r][0] * 0.125f; o.y = acc[r][1] * 0.125f;
        o.z = acc[r][2] * 0.125f; o.w = acc[r][3] * 0.125f;
        *(float4*)&ws[QK_OFF + ((size_t)(bb * L_ + m0 + ty * 4 + r)) * L_ + n0 + tx * 4] = o;
    }
}

// --------------------------------------------------------------------------
// K4: out[b,l,m,n] = qk[b,m,n] + biasK[b,l,n] + biasQ[b,l,m] - masks
__global__ __launch_bounds__(128) void bcast_kernel(
    const int* __restrict__ am, const float* __restrict__ ws, float* __restrict__ out)
{
    const int bm = blockIdx.x;
    const int bb = bm >> 9;
    const int m  = bm & (L_ - 1);
    const int n0 = threadIdx.x * 4;

    float4 qk4 = *(const float4*)&ws[QK_OFF + ((size_t)(bb * L_ + m)) * L_ + n0];
    float amm = (float)am[bb * L_ + m];
    int4 amn = *(const int4*)&am[bb * L_ + n0];

    float4 base;
    base.x = qk4.x - (1.0f - amm * (float)amn.x) * INF_ - ((n0 + 0 < m) ? INF_ : 0.0f);
    base.y = qk4.y - (1.0f - amm * (float)amn.y) * INF_ - ((n0 + 1 < m) ? INF_ : 0.0f);
    base.z = qk4.z - (1.0f - amm * (float)amn.z) * INF_ - ((n0 + 2 < m) ? INF_ : 0.0f);
    base.w = qk4.w - (1.0f - amm * (float)amn.w) * INF_ - ((n0 + 3 < m) ? INF_ : 0.0f);

    #pragma unroll
    for (int l = 0; l < NL; l++) {
        float  bq  = ws[BQ_OFF + ((size_t)bb * NL + l) * L_ + m];
        float4 bk4 = *(const float4*)&ws[BK_OFF + ((size_t)bb * NL + l) * L_ + n0];
        float4 o;
        o.x = base.x + bk4.x + bq;
        o.y = base.y + bk4.y + bq;
        o.z = base.z + bk4.z + bq;
        o.w = base.w + bk4.w + bq;
        *(float4*)&out[(((size_t)(bb * NL + l)) * L_ + m) * L_ + n0] = o;
    }
}

// --------------------------------------------------------------------------
extern "C" void kernel_launch(void* const* d_in, const int* in_sizes, int n_in,
                              void* d_out, int out_size, void* d_ws, size_t ws_size,
                              hipStream_t stream) {
    const float* X  = (const float*)d_in[0];
    const int*   am = (const int*)d_in[1];
    const float* W1 = (const float*)d_in[2];
    const float* b1 = (const float*)d_in[3];
    const float* W2 = (const float*)d_in[4];
    const float* b2 = (const float*)d_in[5];
    float* out = (float*)d_out;
    float* ws  = (float*)d_ws;

    rope_table_kernel<<<64, 256, 0, stream>>>(ws);
    w1t_kernel<<<16, 256, 0, stream>>>(W1, ws);
    gemm1_fused_kernel<<<(B_ * L_) / 16, 256, 0, stream>>>(X, b1, W2, b2, ws);
    qk_kernel<<<B_ * (L_ / 64) * (L_ / 64), 256, 0, stream>>>(ws);
    bcast_kernel<<<B_ * L_, 128, 0, stream>>>(am, ws, out);
}

// Round 3
// 60.358 us; speedup vs baseline: 1.9634x; 1.0057x over previous
//
#include <hip/hip_runtime.h>
#include <math.h>

#define B_   8
#define L_   512
#define DIN  1024
#define H_   128
#define HEAD 64
#define NL   16
#define INF_ 1.0e12f

// ws layout (float offsets)
#define SIN_OFF  0
#define COS_OFF  (512*32)
#define QROT_OFF (COS_OFF + 512*32)            // 32768
#define KROT_OFF (QROT_OFF + B_*L_*HEAD)
#define BQ_OFF   (KROT_OFF + B_*L_*HEAD)       // odd channels -> added along m
#define BK_OFF   (BQ_OFF + B_*NL*L_)           // even channels -> added along n
#define QK_OFF   (BK_OFF + B_*NL*L_)
#define W1T_OFF  (QK_OFF + B_*L_*L_)           // bf16 [n=128][k=1024] = 65536 floats
#define W2T_OFF  (W1T_OFF + 65536)             // bf16 [o=32][k=128]  = 2048 floats
// total floats = W2T_OFF + 2048 = 2,852,864 (~11.4 MB)

typedef float          floatx4  __attribute__((ext_vector_type(4)));
typedef short          shortx8  __attribute__((ext_vector_type(8)));
typedef unsigned short ushortx8 __attribute__((ext_vector_type(8)));

__device__ __forceinline__ unsigned short f2bf(float f) {
    unsigned u = __float_as_uint(f);
    u += 0x7FFFu + ((u >> 16) & 1u);   // RNE
    return (unsigned short)(u >> 16);
}

// --------------------------------------------------------------------------
// prep: blocks 0..63 rope table (f64); 64..79 W1->W1T bf16; 80 W2->W2T bf16
__global__ __launch_bounds__(256) void prep_kernel(const float* __restrict__ W1,
                                                   const float* __restrict__ W2,
                                                   float* __restrict__ ws) {
    __shared__ float lds[64 * 132];
    const int tid = threadIdx.x;
    const int bid = blockIdx.x;

    if (bid < 64) {
        int idx = bid * 256 + tid;
        int m = idx >> 5, i = idx & 31;
        double ang = (double)m * pow(10000.0, -(double)i / 32.0);
        ws[SIN_OFF + idx] = (float)sin(ang);
        ws[COS_OFF + idx] = (float)cos(ang);
    } else if (bid < 80) {
        const int k0 = (bid - 64) * 64;
        for (int i = 0; i < 8; i++) {
            int f = tid + i * 256;              // float4 index over 2048
            int k = f >> 5, n4 = (f & 31) * 4;
            *(float4*)&lds[k * 132 + n4] = *(const float4*)&W1[(size_t)(k0 + k) * H_ + n4];
        }
        __syncthreads();
        unsigned short* W1T = (unsigned short*)(ws + W1T_OFF);
        const int n  = tid >> 1;
        const int kh = (tid & 1) * 32;
        for (int i = 0; i < 4; i++) {
            ushortx8 p;
            #pragma unroll
            for (int j = 0; j < 8; j++) p[j] = f2bf(lds[(kh + i * 8 + j) * 132 + n]);
            *(ushortx8*)&W1T[(size_t)n * DIN + k0 + kh + i * 8] = p;
        }
    } else {
        // W2 [128][32] -> W2T bf16 [32][128]
        unsigned short* W2T = (unsigned short*)(ws + W2T_OFF);
        const int o  = tid >> 3;          // 0..31
        const int kc = (tid & 7) * 16;    // 0..112
        ushortx8 p0, p1;
        #pragma unroll
        for (int j = 0; j < 8; j++) p0[j] = f2bf(W2[(size_t)(kc + j) * 32 + o]);
        #pragma unroll
        for (int j = 0; j < 8; j++) p1[j] = f2bf(W2[(size_t)(kc + 8 + j) * 32 + o]);
        *(ushortx8*)&W2T[(size_t)o * H_ + kc]     = p0;
        *(ushortx8*)&W2T[(size_t)o * H_ + kc + 8] = p1;
    }
}

// --------------------------------------------------------------------------
// K2: h = X@W1 + b1 via bf16 MFMA, direct global->reg fragments (no LDS tiles).
// BM=16 per block, 4 waves x 2 n-tiles. Epilogue: rotary + bias MFMA (wave 0).
__global__ __launch_bounds__(256) void gemm1_fused_kernel(
    const float* __restrict__ X, const float* __restrict__ b1,
    const float* __restrict__ b2, float* __restrict__ ws)
{
    __shared__ float hs[16 * 132];

    const int tid  = threadIdx.x;
    const int m0   = blockIdx.x * 16;
    const int w    = tid >> 6;
    const int lane = tid & 63;
    const int lrow = lane >> 4;          // 0..3
    const int lcol = lane & 15;          // 0..15

    const unsigned short* W1T = (const unsigned short*)(ws + W1T_OFF);

    const float* pA = X + (size_t)(m0 + lcol) * DIN + lrow * 8;
    const unsigned short* pB0 = W1T + (size_t)(w * 32 + lcol) * DIN + lrow * 8;
    const unsigned short* pB1 = pB0 + (size_t)16 * DIN;

    floatx4 acc0 = {0.f, 0.f, 0.f, 0.f};
    floatx4 acc1 = {0.f, 0.f, 0.f, 0.f};

    #pragma unroll
    for (int s = 0; s < 32; s++) {
        float4 a0 = *(const float4*)(pA + s * 32);
        float4 a1 = *(const float4*)(pA + s * 32 + 4);
        shortx8 bf0 = *(const shortx8*)(pB0 + s * 32);
        shortx8 bf1 = *(const shortx8*)(pB1 + s * 32);
        ushortx8 afu;
        afu[0] = f2bf(a0.x); afu[1] = f2bf(a0.y); afu[2] = f2bf(a0.z); afu[3] = f2bf(a0.w);
        afu[4] = f2bf(a1.x); afu[5] = f2bf(a1.y); afu[6] = f2bf(a1.z); afu[7] = f2bf(a1.w);
        shortx8 af = (shortx8)afu;
        acc0 = __builtin_amdgcn_mfma_f32_16x16x32_bf16(af, bf0, acc0, 0, 0, 0);
        acc1 = __builtin_amdgcn_mfma_f32_16x16x32_bf16(af, bf1, acc1, 0, 0, 0);
    }

    // acc -> hs (+b1). C layout: col=lane&15, row=(lane>>4)*4+r  [m89]
    {
        float b1a = b1[w * 32 + lcol];
        float b1b = b1[w * 32 + 16 + lcol];
        #pragma unroll
        for (int r = 0; r < 4; r++) {
            hs[(lrow * 4 + r) * 132 + w * 32 + lcol]      = acc0[r] + b1a;
            hs[(lrow * 4 + r) * 132 + w * 32 + 16 + lcol] = acc1[r] + b1b;
        }
    }
    __syncthreads();

    // rotary: thread -> (row 0..15, j 0..15); outputs d = 4j..4j+3
    {
        int row = tid >> 4;
        int j   = tid & 15;
        int g   = m0 + row;
        int pos = g & (L_ - 1);
        const float* hr = &hs[row * 132];
        float h0 = hr[8 * j + 0], h1 = hr[8 * j + 1];
        float h2 = hr[8 * j + 2], h3 = hr[8 * j + 3];
        float h4 = hr[8 * j + 4], h5 = hr[8 * j + 5];
        float h6 = hr[8 * j + 6], h7 = hr[8 * j + 7];
        float s0 = ws[SIN_OFF + pos * 32 + 2 * j];
        float c0 = ws[COS_OFF + pos * 32 + 2 * j];
        float s1 = ws[SIN_OFF + pos * 32 + 2 * j + 1];
        float c1 = ws[COS_OFF + pos * 32 + 2 * j + 1];
        float4 q, k;
        q.x = h0 * c0 - h2 * s0;  q.y = h2 * c0 + h0 * s0;
        q.z = h4 * c1 - h6 * s1;  q.w = h6 * c1 + h4 * s1;
        k.x = h1 * c0 - h3 * s0;  k.y = h3 * c0 + h1 * s0;
        k.z = h5 * c1 - h7 * s1;  k.w = h7 * c1 + h5 * s1;
        *(float4*)&ws[QROT_OFF + (size_t)g * HEAD + 4 * j] = q;
        *(float4*)&ws[KROT_OFF + (size_t)g * HEAD + 4 * j] = k;
    }

    // bias = (h @ W2 + b2) * 0.5 via MFMA on wave 0: M=16, N=32 (2 tiles), K=128
    if (w == 0) {
        const unsigned short* W2T = (const unsigned short*)(ws + W2T_OFF);
        floatx4 bacc0 = {0.f, 0.f, 0.f, 0.f};
        floatx4 bacc1 = {0.f, 0.f, 0.f, 0.f};
        #pragma unroll
        for (int s = 0; s < 4; s++) {
            int k = s * 32 + lrow * 8;
            ushortx8 hfu;
            #pragma unroll
            for (int j = 0; j < 8; j++) hfu[j] = f2bf(hs[lcol * 132 + k + j]);
            shortx8 hf = (shortx8)hfu;
            shortx8 wf0 = *(const shortx8*)(W2T + (size_t)lcol * H_ + k);
            shortx8 wf1 = *(const shortx8*)(W2T + (size_t)(16 + lcol) * H_ + k);
            bacc0 = __builtin_amdgcn_mfma_f32_16x16x32_bf16(hf, wf0, bacc0, 0, 0, 0);
            bacc1 = __builtin_amdgcn_mfma_f32_16x16x32_bf16(hf, wf1, bacc1, 0, 0, 0);
        }
        float b2a = b2[lcol], b2b = b2[16 + lcol];
        #pragma unroll
        for (int r = 0; r < 4; r++) {
            int g   = m0 + lrow * 4 + r;
            int bb  = g >> 9;
            int pos = g & (L_ - 1);
            float v0 = (bacc0[r] + b2a) * 0.5f;
            float v1 = (bacc1[r] + b2b) * 0.5f;
            int o0 = lcol, o1 = 16 + lcol;
            if (o0 & 1) ws[BQ_OFF + ((size_t)bb * NL + (o0 >> 1)) * L_ + pos] = v0;
            else        ws[BK_OFF + ((size_t)bb * NL + (o0 >> 1)) * L_ + pos] = v0;
            if (o1 & 1) ws[BQ_OFF + ((size_t)bb * NL + (o1 >> 1)) * L_ + pos] = v1;
            else        ws[BK_OFF + ((size_t)bb * NL + (o1 >> 1)) * L_ + pos] = v1;
        }
    }
}

// --------------------------------------------------------------------------
// K3: qk[b,m,n] = dot(qrot[b,m,:], krot[b,n,:]) * 0.125; 64x64 tiles, K=64.
__global__ __launch_bounds__(256) void qk_kernel(float* __restrict__ ws)
{
    __shared__ float Qs[64][68];
    __shared__ float Ks[64][68];

    const int tid = threadIdx.x;
    const int bid = blockIdx.x;
    const int bb = bid >> 6;
    const int mt = (bid >> 3) & 7;
    const int nt = bid & 7;
    const int m0 = mt * 64, n0 = nt * 64;

    {
        int r0   = tid >> 4;
        int dcol = (tid & 15) * 4;
        #pragma unroll
        for (int rr = 0; rr < 4; rr++) {
            int r = r0 + rr * 16;
            float4 q = *(const float4*)&ws[QROT_OFF + ((size_t)(bb * L_ + m0 + r)) * HEAD + dcol];
            float4 k = *(const float4*)&ws[KROT_OFF + ((size_t)(bb * L_ + n0 + r)) * HEAD + dcol];
            Qs[dcol + 0][r] = q.x; Qs[dcol + 1][r] = q.y;
            Qs[dcol + 2][r] = q.z; Qs[dcol + 3][r] = q.w;
            Ks[dcol + 0][r] = k.x; Ks[dcol + 1][r] = k.y;
            Ks[dcol + 2][r] = k.z; Ks[dcol + 3][r] = k.w;
        }
    }
    __syncthreads();

    const int ty = tid >> 4;
    const int tx = tid & 15;
    float acc[4][4] = {};
    #pragma unroll 8
    for (int d = 0; d < HEAD; d++) {
        float4 a  = *(const float4*)&Qs[d][ty * 4];
        float4 bv = *(const float4*)&Ks[d][tx * 4];
        acc[0][0] += a.x * bv.x; acc[0][1] += a.x * bv.y; acc[0][2] += a.x * bv.z; acc[0][3] += a.x * bv.w;
        acc[1][0] += a.y * bv.x; acc[1][1] += a.y * bv.y; acc[1][2] += a.y * bv.z; acc[1][3] += a.y * bv.w;
        acc[2][0] += a.z * bv.x; acc[2][1] += a.z * bv.y; acc[2][2] += a.z * bv.z; acc[2][3] += a.z * bv.w;
        acc[3][0] += a.w * bv.x; acc[3][1] += a.w * bv.y; acc[3][2] += a.w * bv.z; acc[3][3] += a.w * bv.w;
    }

    #pragma unroll
    for (int r = 0; r < 4; r++) {
        float4 o;
        o.x = acc[r][0] * 0.125f; o.y = acc[r][1] * 0.125f;
        o.z = acc[r][2] * 0.125f; o.w = acc[r][3] * 0.125f;
        *(float4*)&ws[QK_OFF + ((size_t)(bb * L_ + m0 + ty * 4 + r)) * L_ + n0 + tx * 4] = o;
    }
}

// --------------------------------------------------------------------------
// K4: out[b,l,m,n] = qk[b,m,n] + biasK[b,l,n] + biasQ[b,l,m] - masks
__global__ __launch_bounds__(128) void bcast_kernel(
    const int* __restrict__ am, const float* __restrict__ ws, float* __restrict__ out)
{
    const int bm = blockIdx.x;
    const int bb = bm >> 9;
    const int m  = bm & (L_ - 1);
    const int n0 = threadIdx.x * 4;

    float4 qk4 = *(const float4*)&ws[QK_OFF + ((size_t)(bb * L_ + m)) * L_ + n0];
    float amm = (float)am[bb * L_ + m];
    int4 amn = *(const int4*)&am[bb * L_ + n0];

    float4 base;
    base.x = qk4.x - (1.0f - amm * (float)amn.x) * INF_ - ((n0 + 0 < m) ? INF_ : 0.0f);
    base.y = qk4.y - (1.0f - amm * (float)amn.y) * INF_ - ((n0 + 1 < m) ? INF_ : 0.0f);
    base.z = qk4.z - (1.0f - amm * (float)amn.z) * INF_ - ((n0 + 2 < m) ? INF_ : 0.0f);
    base.w = qk4.w - (1.0f - amm * (float)amn.w) * INF_ - ((n0 + 3 < m) ? INF_ : 0.0f);

    #pragma unroll
    for (int l = 0; l < NL; l++) {
        float  bq  = ws[BQ_OFF + ((size_t)bb * NL + l) * L_ + m];
        float4 bk4 = *(const float4*)&ws[BK_OFF + ((size_t)bb * NL + l) * L_ + n0];
        float4 o;
        o.x = base.x + bk4.x + bq;
        o.y = base.y + bk4.y + bq;
        o.z = base.z + bk4.z + bq;
        o.w = base.w + bk4.w + bq;
        *(float4*)&out[(((size_t)(bb * NL + l)) * L_ + m) * L_ + n0] = o;
    }
}

// --------------------------------------------------------------------------
extern "C" void kernel_launch(void* const* d_in, const int* in_sizes, int n_in,
                              void* d_out, int out_size, void* d_ws, size_t ws_size,
                              hipStream_t stream) {
    const float* X  = (const float*)d_in[0];
    const int*   am = (const int*)d_in[1];
    const float* W1 = (const float*)d_in[2];
    const float* b1 = (const float*)d_in[3];
    const float* W2 = (const float*)d_in[4];
    const float* b2 = (const float*)d_in[5];
    float* out = (float*)d_out;
    float* ws  = (float*)d_ws;

    prep_kernel<<<81, 256, 0, stream>>>(W1, W2, ws);
    gemm1_fused_kernel<<<(B_ * L_) / 16, 256, 0, stream>>>(X, b1, b2, ws);
    qk_kernel<<<B_ * (L_ / 64) * (L_ / 64), 256, 0, stream>>>(ws);
    bcast_kernel<<<B_ * L_, 128, 0, stream>>>(am, ws, out);
}

// Round 4
// 53.908 us; speedup vs baseline: 2.1983x; 1.1196x over previous
//
#include <hip/hip_runtime.h>
#include <math.h>

#define B_   8
#define L_   512
#define DIN  1024
#define H_   128
#define HEAD 64
#define NL   16
#define INF_ 1.0e12f

// ws layout (float offsets)
#define SIN_OFF  0
#define COS_OFF  (512*32)
#define QROT_OFF (COS_OFF + 512*32)            // 32768
#define KROT_OFF (QROT_OFF + B_*L_*HEAD)
#define BQ_OFF   (KROT_OFF + B_*L_*HEAD)       // odd channels -> added along m
#define BK_OFF   (BQ_OFF + B_*NL*L_)           // even channels -> added along n
#define W1T_OFF  (BK_OFF + B_*NL*L_)           // bf16 [n=128][k=1024] = 65536 floats
#define W2T_OFF  (W1T_OFF + 65536)             // bf16 [o=32][k=128]  = 2048 floats
// total floats = W2T_OFF + 2048 = ~0.8 MB  (qk intermediate eliminated)

typedef float          floatx4  __attribute__((ext_vector_type(4)));
typedef short          shortx8  __attribute__((ext_vector_type(8)));
typedef unsigned short ushortx8 __attribute__((ext_vector_type(8)));

__device__ __forceinline__ unsigned short f2bf(float f) {
    unsigned u = __float_as_uint(f);
    u += 0x7FFFu + ((u >> 16) & 1u);   // RNE
    return (unsigned short)(u >> 16);
}

// --------------------------------------------------------------------------
// prep: blocks 0..63 rope table (f64); 64..79 W1->W1T bf16; 80 W2->W2T bf16
__global__ __launch_bounds__(256) void prep_kernel(const float* __restrict__ W1,
                                                   const float* __restrict__ W2,
                                                   float* __restrict__ ws) {
    __shared__ float lds[64 * 132];
    const int tid = threadIdx.x;
    const int bid = blockIdx.x;

    if (bid < 64) {
        int idx = bid * 256 + tid;
        int m = idx >> 5, i = idx & 31;
        double ang = (double)m * pow(10000.0, -(double)i / 32.0);
        ws[SIN_OFF + idx] = (float)sin(ang);
        ws[COS_OFF + idx] = (float)cos(ang);
    } else if (bid < 80) {
        const int k0 = (bid - 64) * 64;
        for (int i = 0; i < 8; i++) {
            int f = tid + i * 256;              // float4 index over 2048
            int k = f >> 5, n4 = (f & 31) * 4;
            *(float4*)&lds[k * 132 + n4] = *(const float4*)&W1[(size_t)(k0 + k) * H_ + n4];
        }
        __syncthreads();
        unsigned short* W1T = (unsigned short*)(ws + W1T_OFF);
        const int n  = tid >> 1;
        const int kh = (tid & 1) * 32;
        for (int i = 0; i < 4; i++) {
            ushortx8 p;
            #pragma unroll
            for (int j = 0; j < 8; j++) p[j] = f2bf(lds[(kh + i * 8 + j) * 132 + n]);
            *(ushortx8*)&W1T[(size_t)n * DIN + k0 + kh + i * 8] = p;
        }
    } else {
        // W2 [128][32] -> W2T bf16 [32][128]
        unsigned short* W2T = (unsigned short*)(ws + W2T_OFF);
        const int o  = tid >> 3;          // 0..31
        const int kc = (tid & 7) * 16;    // 0..112
        ushortx8 p0, p1;
        #pragma unroll
        for (int j = 0; j < 8; j++) p0[j] = f2bf(W2[(size_t)(kc + j) * 32 + o]);
        #pragma unroll
        for (int j = 0; j < 8; j++) p1[j] = f2bf(W2[(size_t)(kc + 8 + j) * 32 + o]);
        *(ushortx8*)&W2T[(size_t)o * H_ + kc]     = p0;
        *(ushortx8*)&W2T[(size_t)o * H_ + kc + 8] = p1;
    }
}

// --------------------------------------------------------------------------
// K2: h = X@W1 + b1 via bf16 MFMA, direct global->reg fragments (no LDS tiles).
// BM=16 per block, 4 waves x 2 n-tiles. Epilogue: rotary + bias MFMA (wave 0).
__global__ __launch_bounds__(256) void gemm1_fused_kernel(
    const float* __restrict__ X, const float* __restrict__ b1,
    const float* __restrict__ b2, float* __restrict__ ws)
{
    __shared__ float hs[16 * 132];

    const int tid  = threadIdx.x;
    const int m0   = blockIdx.x * 16;
    const int w    = tid >> 6;
    const int lane = tid & 63;
    const int lrow = lane >> 4;          // 0..3
    const int lcol = lane & 15;          // 0..15

    const unsigned short* W1T = (const unsigned short*)(ws + W1T_OFF);

    const float* pA = X + (size_t)(m0 + lcol) * DIN + lrow * 8;
    const unsigned short* pB0 = W1T + (size_t)(w * 32 + lcol) * DIN + lrow * 8;
    const unsigned short* pB1 = pB0 + (size_t)16 * DIN;

    floatx4 acc0 = {0.f, 0.f, 0.f, 0.f};
    floatx4 acc1 = {0.f, 0.f, 0.f, 0.f};

    #pragma unroll
    for (int s = 0; s < 32; s++) {
        float4 a0 = *(const float4*)(pA + s * 32);
        float4 a1 = *(const float4*)(pA + s * 32 + 4);
        shortx8 bf0 = *(const shortx8*)(pB0 + s * 32);
        shortx8 bf1 = *(const shortx8*)(pB1 + s * 32);
        ushortx8 afu;
        afu[0] = f2bf(a0.x); afu[1] = f2bf(a0.y); afu[2] = f2bf(a0.z); afu[3] = f2bf(a0.w);
        afu[4] = f2bf(a1.x); afu[5] = f2bf(a1.y); afu[6] = f2bf(a1.z); afu[7] = f2bf(a1.w);
        shortx8 af = (shortx8)afu;
        acc0 = __builtin_amdgcn_mfma_f32_16x16x32_bf16(af, bf0, acc0, 0, 0, 0);
        acc1 = __builtin_amdgcn_mfma_f32_16x16x32_bf16(af, bf1, acc1, 0, 0, 0);
    }

    // acc -> hs (+b1). C layout: col=lane&15, row=(lane>>4)*4+r  [m89]
    {
        float b1a = b1[w * 32 + lcol];
        float b1b = b1[w * 32 + 16 + lcol];
        #pragma unroll
        for (int r = 0; r < 4; r++) {
            hs[(lrow * 4 + r) * 132 + w * 32 + lcol]      = acc0[r] + b1a;
            hs[(lrow * 4 + r) * 132 + w * 32 + 16 + lcol] = acc1[r] + b1b;
        }
    }
    __syncthreads();

    // rotary: thread -> (row 0..15, j 0..15); outputs d = 4j..4j+3
    {
        int row = tid >> 4;
        int j   = tid & 15;
        int g   = m0 + row;
        int pos = g & (L_ - 1);
        const float* hr = &hs[row * 132];
        float h0 = hr[8 * j + 0], h1 = hr[8 * j + 1];
        float h2 = hr[8 * j + 2], h3 = hr[8 * j + 3];
        float h4 = hr[8 * j + 4], h5 = hr[8 * j + 5];
        float h6 = hr[8 * j + 6], h7 = hr[8 * j + 7];
        float s0 = ws[SIN_OFF + pos * 32 + 2 * j];
        float c0 = ws[COS_OFF + pos * 32 + 2 * j];
        float s1 = ws[SIN_OFF + pos * 32 + 2 * j + 1];
        float c1 = ws[COS_OFF + pos * 32 + 2 * j + 1];
        float4 q, k;
        q.x = h0 * c0 - h2 * s0;  q.y = h2 * c0 + h0 * s0;
        q.z = h4 * c1 - h6 * s1;  q.w = h6 * c1 + h4 * s1;
        k.x = h1 * c0 - h3 * s0;  k.y = h3 * c0 + h1 * s0;
        k.z = h5 * c1 - h7 * s1;  k.w = h7 * c1 + h5 * s1;
        *(float4*)&ws[QROT_OFF + (size_t)g * HEAD + 4 * j] = q;
        *(float4*)&ws[KROT_OFF + (size_t)g * HEAD + 4 * j] = k;
    }

    // bias = (h @ W2 + b2) * 0.5 via MFMA on wave 0: M=16, N=32 (2 tiles), K=128
    if (w == 0) {
        const unsigned short* W2T = (const unsigned short*)(ws + W2T_OFF);
        floatx4 bacc0 = {0.f, 0.f, 0.f, 0.f};
        floatx4 bacc1 = {0.f, 0.f, 0.f, 0.f};
        #pragma unroll
        for (int s = 0; s < 4; s++) {
            int k = s * 32 + lrow * 8;
            ushortx8 hfu;
            #pragma unroll
            for (int j = 0; j < 8; j++) hfu[j] = f2bf(hs[lcol * 132 + k + j]);
            shortx8 hf = (shortx8)hfu;
            shortx8 wf0 = *(const shortx8*)(W2T + (size_t)lcol * H_ + k);
            shortx8 wf1 = *(const shortx8*)(W2T + (size_t)(16 + lcol) * H_ + k);
            bacc0 = __builtin_amdgcn_mfma_f32_16x16x32_bf16(hf, wf0, bacc0, 0, 0, 0);
            bacc1 = __builtin_amdgcn_mfma_f32_16x16x32_bf16(hf, wf1, bacc1, 0, 0, 0);
        }
        float b2a = b2[lcol], b2b = b2[16 + lcol];
        #pragma unroll
        for (int r = 0; r < 4; r++) {
            int g   = m0 + lrow * 4 + r;
            int bb  = g >> 9;
            int pos = g & (L_ - 1);
            float v0 = (bacc0[r] + b2a) * 0.5f;
            float v1 = (bacc1[r] + b2b) * 0.5f;
            int o0 = lcol, o1 = 16 + lcol;
            if (o0 & 1) ws[BQ_OFF + ((size_t)bb * NL + (o0 >> 1)) * L_ + pos] = v0;
            else        ws[BK_OFF + ((size_t)bb * NL + (o0 >> 1)) * L_ + pos] = v0;
            if (o1 & 1) ws[BQ_OFF + ((size_t)bb * NL + (o1 >> 1)) * L_ + pos] = v1;
            else        ws[BK_OFF + ((size_t)bb * NL + (o1 >> 1)) * L_ + pos] = v1;
        }
    }
}

// --------------------------------------------------------------------------
// K3 (fused): per (b, mt, nt) 64x64 tile -> qk in registers -> +bias/masks ->
// 16 l-channel output stores. No qk intermediate.
__global__ __launch_bounds__(256) void qk_bcast_kernel(
    const int* __restrict__ am, const float* __restrict__ ws, float* __restrict__ out)
{
    __shared__ float Qs[64][68];
    __shared__ float Ks[64][68];
    __shared__ float BQs[16][64];
    __shared__ float BKs[16][64];
    __shared__ float maskM[64];
    __shared__ float maskN[64];

    const int tid = threadIdx.x;
    const int bid = blockIdx.x;
    const int bb = bid >> 6;
    const int mt = (bid >> 3) & 7;
    const int nt = bid & 7;
    const int m0 = mt * 64, n0 = nt * 64;

    // stage Q/K transposed
    {
        int r0   = tid >> 4;
        int dcol = (tid & 15) * 4;
        #pragma unroll
        for (int rr = 0; rr < 4; rr++) {
            int r = r0 + rr * 16;
            float4 q = *(const float4*)&ws[QROT_OFF + ((size_t)(bb * L_ + m0 + r)) * HEAD + dcol];
            float4 k = *(const float4*)&ws[KROT_OFF + ((size_t)(bb * L_ + n0 + r)) * HEAD + dcol];
            Qs[dcol + 0][r] = q.x; Qs[dcol + 1][r] = q.y;
            Qs[dcol + 2][r] = q.z; Qs[dcol + 3][r] = q.w;
            Ks[dcol + 0][r] = k.x; Ks[dcol + 1][r] = k.y;
            Ks[dcol + 2][r] = k.z; Ks[dcol + 3][r] = k.w;
        }
    }
    // stage BQ/BK tiles: 16 l x 64
    {
        int l = tid >> 4;
        int c = (tid & 15) * 4;
        *(float4*)&BQs[l][c] = *(const float4*)&ws[BQ_OFF + ((size_t)bb * NL + l) * L_ + m0 + c];
        *(float4*)&BKs[l][c] = *(const float4*)&ws[BK_OFF + ((size_t)bb * NL + l) * L_ + n0 + c];
    }
    if (tid < 64)       maskM[tid]      = (float)am[bb * L_ + m0 + tid];
    else if (tid < 128) maskN[tid - 64] = (float)am[bb * L_ + n0 + (tid - 64)];
    __syncthreads();

    const int ty = tid >> 4;
    const int tx = tid & 15;
    float acc[4][4] = {};
    #pragma unroll 8
    for (int d = 0; d < HEAD; d++) {
        float4 a  = *(const float4*)&Qs[d][ty * 4];
        float4 bv = *(const float4*)&Ks[d][tx * 4];
        acc[0][0] += a.x * bv.x; acc[0][1] += a.x * bv.y; acc[0][2] += a.x * bv.z; acc[0][3] += a.x * bv.w;
        acc[1][0] += a.y * bv.x; acc[1][1] += a.y * bv.y; acc[1][2] += a.y * bv.z; acc[1][3] += a.y * bv.w;
        acc[2][0] += a.z * bv.x; acc[2][1] += a.z * bv.y; acc[2][2] += a.z * bv.z; acc[2][3] += a.z * bv.w;
        acc[3][0] += a.w * bv.x; acc[3][1] += a.w * bv.y; acc[3][2] += a.w * bv.z; acc[3][3] += a.w * bv.w;
    }

    // base = qk*0.125 - attn_mask*INF - tril*INF
    float4 base[4];
    #pragma unroll
    for (int r = 0; r < 4; r++) {
        int m = m0 + ty * 4 + r;
        float mm = maskM[ty * 4 + r];
        #pragma unroll
        for (int c = 0; c < 4; c++) {
            int n = n0 + tx * 4 + c;
            float v = acc[r][c] * 0.125f
                    - (1.0f - mm * maskN[tx * 4 + c]) * INF_
                    - ((n < m) ? INF_ : 0.0f);
            ((float*)&base[r])[c] = v;
        }
    }

    // output: 16 l-channels x 4 rows x float4
    #pragma unroll
    for (int l = 0; l < NL; l++) {
        float4 bk4 = *(const float4*)&BKs[l][tx * 4];
        size_t outb = (((size_t)(bb * NL + l)) * L_ + m0 + ty * 4) * L_ + n0 + tx * 4;
        #pragma unroll
        for (int r = 0; r < 4; r++) {
            float bq = BQs[l][ty * 4 + r];
            float4 o;
            o.x = base[r].x + bk4.x + bq;
            o.y = base[r].y + bk4.y + bq;
            o.z = base[r].z + bk4.z + bq;
            o.w = base[r].w + bk4.w + bq;
            *(float4*)&out[outb + (size_t)r * L_] = o;
        }
    }
}

// --------------------------------------------------------------------------
extern "C" void kernel_launch(void* const* d_in, const int* in_sizes, int n_in,
                              void* d_out, int out_size, void* d_ws, size_t ws_size,
                              hipStream_t stream) {
    const float* X  = (const float*)d_in[0];
    const int*   am = (const int*)d_in[1];
    const float* W1 = (const float*)d_in[2];
    const float* b1 = (const float*)d_in[3];
    const float* W2 = (const float*)d_in[4];
    const float* b2 = (const float*)d_in[5];
    float* out = (float*)d_out;
    float* ws  = (float*)d_ws;

    prep_kernel<<<81, 256, 0, stream>>>(W1, W2, ws);
    gemm1_fused_kernel<<<(B_ * L_) / 16, 256, 0, stream>>>(X, b1, b2, ws);
    qk_bcast_kernel<<<B_ * (L_ / 64) * (L_ / 64), 256, 0, stream>>>(am, ws, out);
}